// Round 13
// baseline (770.492 us; speedup 1.0000x reference)
//
#include <hip/hip_runtime.h>
#include <hip/hip_fp16.h>
#include <math.h>

#define MAXBKT 512   // buckets of 256 dst nodes; N=100K -> 391 buckets

// ---------------- CSR build (bucket sort, block-exclusive writes) ----------

__global__ __launch_bounds__(256) void k_bcount(const int* __restrict__ dstA,
                                                int E, int N, int nbkt, int* bucketCnt) {
    __shared__ int cnt[MAXBKT];
    for (int i = threadIdx.x; i < nbkt; i += 256) cnt[i] = 0;
    __syncthreads();
    int total = E + N;
    for (int i = blockIdx.x * 256 + threadIdx.x; i < total; i += gridDim.x * 256) {
        int d = (i < E) ? dstA[i] : (i - E);
        atomicAdd(&cnt[d >> 8], 1);
    }
    __syncthreads();
    for (int i = threadIdx.x; i < nbkt; i += 256)
        if (cnt[i]) atomicAdd(&bucketCnt[i], cnt[i]);
}

__global__ __launch_bounds__(MAXBKT) void k_bscan(const int* __restrict__ bucketCnt,
                                                  int* bucketOff, int* bucketCur,
                                                  int nbkt, int total) {
    __shared__ int sm[MAXBKT];
    int tid = threadIdx.x;
    int v = (tid < nbkt) ? bucketCnt[tid] : 0;
    sm[tid] = v;
    __syncthreads();
    for (int off = 1; off < MAXBKT; off <<= 1) {
        int t = 0;
        if (tid >= off) t = sm[tid - off];
        __syncthreads();
        sm[tid] += t;
        __syncthreads();
    }
    if (tid < nbkt) {
        int excl = sm[tid] - v;
        bucketOff[tid] = excl;
        bucketCur[tid] = excl;
    }
    if (tid == 0) bucketOff[nbkt] = total;
}

__global__ __launch_bounds__(256) void k_bscat2(const int* __restrict__ srcA,
                                                const int* __restrict__ dstA,
                                                int* bucketCur, unsigned int* bedges,
                                                int E, int N, int nbkt, int chunk) {
    __shared__ int cnt[MAXBKT];
    __shared__ int base[MAXBKT];
    int total = E + N;
    int lo = blockIdx.x * chunk;
    int hi = lo + chunk; if (hi > total) hi = total;
    for (int i = threadIdx.x; i < nbkt; i += 256) cnt[i] = 0;
    __syncthreads();
    for (int i = lo + threadIdx.x; i < hi; i += 256) {
        int d = (i < E) ? dstA[i] : (i - E);
        atomicAdd(&cnt[d >> 8], 1);
    }
    __syncthreads();
    for (int i = threadIdx.x; i < nbkt; i += 256) {
        base[i] = cnt[i] ? atomicAdd(&bucketCur[i], cnt[i]) : 0;
        cnt[i] = 0;
    }
    __syncthreads();
    for (int i = lo + threadIdx.x; i < hi; i += 256) {
        int s, d;
        if (i < E) { s = srcA[i]; d = dstA[i]; }
        else       { s = d = i - E; }
        int b = d >> 8;
        int pos = base[b] + atomicAdd(&cnt[b], 1);
        bedges[pos] = ((unsigned int)(d & 255) << 24) | (unsigned int)s;
    }
}

// one block per bucket: degree count -> scan -> rowptr + dinv + xs, then col.
__global__ __launch_bounds__(256) void k_bfill2(const unsigned int* __restrict__ bedges,
                                                const int* __restrict__ bucketOff,
                                                const float* __restrict__ x,
                                                int* __restrict__ rowptr,
                                                float* __restrict__ dinv,
                                                float* __restrict__ xs,
                                                int* __restrict__ col,
                                                int N, int total) {
    __shared__ int ldeg[256];
    __shared__ int lcur[256];
    int b = blockIdx.x;
    int tid = threadIdx.x;
    int bo = bucketOff[b], be = bucketOff[b + 1];
    ldeg[tid] = 0;
    __syncthreads();
    for (int j = bo + tid; j < be; j += 256)
        atomicAdd(&ldeg[bedges[j] >> 24], 1);
    __syncthreads();
    int dg = ldeg[tid];
    lcur[tid] = dg;
    __syncthreads();
    for (int off = 1; off < 256; off <<= 1) {
        int t = 0;
        if (tid >= off) t = lcur[tid - off];
        __syncthreads();
        lcur[tid] += t;
        __syncthreads();
    }
    int excl = lcur[tid] - dg;
    int node = (b << 8) + tid;
    if (node < N) {
        rowptr[node] = bo + excl;
        float dv = dg > 0 ? rsqrtf((float)dg) : 0.0f;
        dinv[node] = dv;
        xs[node * 3 + 0] = dv * x[node * 3 + 0];
        xs[node * 3 + 1] = dv * x[node * 3 + 1];
        xs[node * 3 + 2] = dv * x[node * 3 + 2];
    }
    if (b == 0 && tid == 0) rowptr[N] = total;
    __syncthreads();
    lcur[tid] = bo + excl;
    __syncthreads();
    for (int j = bo + tid; j < be; j += 256) {
        unsigned int e = bedges[j];
        int pos = atomicAdd(&lcur[e >> 24], 1);
        col[pos] = (int)(e & 0x00FFFFFFu);
    }
}

// ---------------- layer kernels ----------------

__global__ __launch_bounds__(256) void k_agg3(const float* __restrict__ xs,
                                              const int* __restrict__ rowptr,
                                              const int* __restrict__ col,
                                              const float* __restrict__ dinv,
                                              float* __restrict__ out3, int n) {
    int i = blockIdx.x * 256 + threadIdx.x;
    if (i >= n) return;
    float a0 = 0.f, a1 = 0.f, a2 = 0.f;
    int beg = rowptr[i], end = rowptr[i + 1];
    for (int j = beg; j < end; ++j) {
        int s = col[j];
        a0 += xs[s * 3 + 0];
        a1 += xs[s * 3 + 1];
        a2 += xs[s * 3 + 2];
    }
    float dv = dinv[i];
    out3[i * 3 + 0] = dv * a0;
    out3[i * 3 + 1] = dv * a1;
    out3[i * 3 + 2] = dv * a2;
}

// fused input: h0 = relu(agg3 @ Win + bin) [LDS]; t1 = fp16(dinv * (h0 @ W0))
// 512 threads, 8 nodes/block, 1 output feature per thread.
__global__ __launch_bounds__(512) void k_tin_mm(const float* __restrict__ agg3v,
                                                const float* __restrict__ Win,
                                                const float* __restrict__ bin,
                                                const float* __restrict__ W0,
                                                const float* __restrict__ dinv,
                                                __half* __restrict__ tout, int n) {
    __shared__ float Wl[64 * 64];
    __shared__ float Hl[8][68];
    int tid = threadIdx.x;
    {
        int i = tid * 4;
        *(float4*)&Wl[i] = *(const float4*)&W0[i];
        *(float4*)&Wl[i + 2048] = *(const float4*)&W0[i + 2048];
    }
    int nodeBase = blockIdx.x * 8;
    int nl = tid >> 6, f = tid & 63;
    int node = nodeBase + nl;
    if (node < n) {
        float a0 = agg3v[node * 3 + 0];
        float a1 = agg3v[node * 3 + 1];
        float a2 = agg3v[node * 3 + 2];
        float v = bin[f] + a0 * Win[f] + a1 * Win[64 + f] + a2 * Win[128 + f];
        Hl[nl][f] = fmaxf(v, 0.f);
    }
    __syncthreads();
    if (node < n) {
        float acc = 0.f;
#pragma unroll
        for (int k = 0; k < 64; ++k) acc += Hl[nl][k] * Wl[k * 64 + f];
        tout[(size_t)node * 64 + f] = __float2half(acc * dinv[node]);
    }
}

// fused hidden layer: 512 threads, 8 waves, 1 node per wave (no k4 bubbles).
// Gather: 64 lanes = 8 edge-slots x 8 feat-lanes, 16B loads, unroll-4.
// Then h -> LDS, block matmul 1 output/thread, fp16 out.
__global__ __launch_bounds__(512) void k_aggmm64(const __half* __restrict__ tin,
                                                 const int* __restrict__ rowptr,
                                                 const int* __restrict__ col,
                                                 const float* __restrict__ dinv,
                                                 const float* __restrict__ bias,
                                                 const float* __restrict__ W,
                                                 __half* __restrict__ tnext, int n) {
    __shared__ float Wl[64 * 64];
    __shared__ float Hl[8][68];
    int tid = threadIdx.x;
    {
        int i = tid * 4;
        *(float4*)&Wl[i] = *(const float4*)&W[i];
        *(float4*)&Wl[i + 2048] = *(const float4*)&W[i + 2048];
    }
    int nodeBase = blockIdx.x * 8;
    int wv = tid >> 6;
    int lane = tid & 63;
    int slot = lane >> 3;
    int fl = lane & 7;
    int node = nodeBase + wv;
    float a0 = 0.f, a1 = 0.f, a2 = 0.f, a3 = 0.f, a4 = 0.f, a5 = 0.f, a6 = 0.f, a7 = 0.f;
    if (node < n) {
        int beg = rowptr[node], end = rowptr[node + 1];
        int j = beg + slot;
        for (; j + 24 < end; j += 32) {   // 4 independent gathers in flight
            int s0 = col[j], s1 = col[j + 8], s2 = col[j + 16], s3 = col[j + 24];
            float4 r0 = *(const float4*)(tin + (size_t)s0 * 64 + fl * 8);
            float4 r1 = *(const float4*)(tin + (size_t)s1 * 64 + fl * 8);
            float4 r2 = *(const float4*)(tin + (size_t)s2 * 64 + fl * 8);
            float4 r3 = *(const float4*)(tin + (size_t)s3 * 64 + fl * 8);
            const __half2* h0 = (const __half2*)&r0;
            const __half2* h1 = (const __half2*)&r1;
            const __half2* h2 = (const __half2*)&r2;
            const __half2* h3 = (const __half2*)&r3;
            float2 p;
            p = __half22float2(h0[0]); a0 += p.x; a1 += p.y;
            p = __half22float2(h0[1]); a2 += p.x; a3 += p.y;
            p = __half22float2(h0[2]); a4 += p.x; a5 += p.y;
            p = __half22float2(h0[3]); a6 += p.x; a7 += p.y;
            p = __half22float2(h1[0]); a0 += p.x; a1 += p.y;
            p = __half22float2(h1[1]); a2 += p.x; a3 += p.y;
            p = __half22float2(h1[2]); a4 += p.x; a5 += p.y;
            p = __half22float2(h1[3]); a6 += p.x; a7 += p.y;
            p = __half22float2(h2[0]); a0 += p.x; a1 += p.y;
            p = __half22float2(h2[1]); a2 += p.x; a3 += p.y;
            p = __half22float2(h2[2]); a4 += p.x; a5 += p.y;
            p = __half22float2(h2[3]); a6 += p.x; a7 += p.y;
            p = __half22float2(h3[0]); a0 += p.x; a1 += p.y;
            p = __half22float2(h3[1]); a2 += p.x; a3 += p.y;
            p = __half22float2(h3[2]); a4 += p.x; a5 += p.y;
            p = __half22float2(h3[3]); a6 += p.x; a7 += p.y;
        }
        for (; j < end; j += 8) {
            int s0 = col[j];
            float4 r0 = *(const float4*)(tin + (size_t)s0 * 64 + fl * 8);
            const __half2* h0 = (const __half2*)&r0;
            float2 p;
            p = __half22float2(h0[0]); a0 += p.x; a1 += p.y;
            p = __half22float2(h0[1]); a2 += p.x; a3 += p.y;
            p = __half22float2(h0[2]); a4 += p.x; a5 += p.y;
            p = __half22float2(h0[3]); a6 += p.x; a7 += p.y;
        }
    }
#pragma unroll
    for (int m = 8; m < 64; m <<= 1) {
        a0 += __shfl_xor(a0, m, 64);
        a1 += __shfl_xor(a1, m, 64);
        a2 += __shfl_xor(a2, m, 64);
        a3 += __shfl_xor(a3, m, 64);
        a4 += __shfl_xor(a4, m, 64);
        a5 += __shfl_xor(a5, m, 64);
        a6 += __shfl_xor(a6, m, 64);
        a7 += __shfl_xor(a7, m, 64);
    }
    if (slot == 0 && node < n) {
        float dv = dinv[node];
        int fo = fl * 8;
        float4 w0, w1;
        w0.x = fmaxf(dv * a0 + bias[fo + 0], 0.f);
        w0.y = fmaxf(dv * a1 + bias[fo + 1], 0.f);
        w0.z = fmaxf(dv * a2 + bias[fo + 2], 0.f);
        w0.w = fmaxf(dv * a3 + bias[fo + 3], 0.f);
        w1.x = fmaxf(dv * a4 + bias[fo + 4], 0.f);
        w1.y = fmaxf(dv * a5 + bias[fo + 5], 0.f);
        w1.z = fmaxf(dv * a6 + bias[fo + 6], 0.f);
        w1.w = fmaxf(dv * a7 + bias[fo + 7], 0.f);
        *(float4*)&Hl[wv][fo] = w0;
        *(float4*)&Hl[wv][fo + 4] = w1;
    }
    __syncthreads();
    // matmul: 1 output feature per thread
    if (node < n) {
        int f = lane;
        float acc = 0.f;
#pragma unroll
        for (int k = 0; k < 64; ++k) acc += Hl[wv][k] * Wl[k * 64 + f];
        tnext[(size_t)node * 64 + f] = __float2half(acc * dinv[node]);
    }
}

// fused last hidden + output transform (512 threads, 8 nodes, 1 node/wave)
__global__ __launch_bounds__(512) void k_aggtout(const __half* __restrict__ tin,
                                                 const int* __restrict__ rowptr,
                                                 const int* __restrict__ col,
                                                 const float* __restrict__ dinv,
                                                 const float* __restrict__ bias,
                                                 const float* __restrict__ Wout,
                                                 __half* __restrict__ t6p, int n) {
    __shared__ float Wl6[64 * 6];
    __shared__ float Hl[8][68];
    int tid = threadIdx.x;
    if (tid < 384) Wl6[tid] = Wout[tid];
    int nodeBase = blockIdx.x * 8;
    int wv = tid >> 6;
    int lane = tid & 63;
    int slot = lane >> 3;
    int fl = lane & 7;
    int node = nodeBase + wv;
    float a0 = 0.f, a1 = 0.f, a2 = 0.f, a3 = 0.f, a4 = 0.f, a5 = 0.f, a6 = 0.f, a7 = 0.f;
    if (node < n) {
        int beg = rowptr[node], end = rowptr[node + 1];
        int j = beg + slot;
        for (; j + 24 < end; j += 32) {
            int s0 = col[j], s1 = col[j + 8], s2 = col[j + 16], s3 = col[j + 24];
            float4 r0 = *(const float4*)(tin + (size_t)s0 * 64 + fl * 8);
            float4 r1 = *(const float4*)(tin + (size_t)s1 * 64 + fl * 8);
            float4 r2 = *(const float4*)(tin + (size_t)s2 * 64 + fl * 8);
            float4 r3 = *(const float4*)(tin + (size_t)s3 * 64 + fl * 8);
            const __half2* h0 = (const __half2*)&r0;
            const __half2* h1 = (const __half2*)&r1;
            const __half2* h2 = (const __half2*)&r2;
            const __half2* h3 = (const __half2*)&r3;
            float2 p;
            p = __half22float2(h0[0]); a0 += p.x; a1 += p.y;
            p = __half22float2(h0[1]); a2 += p.x; a3 += p.y;
            p = __half22float2(h0[2]); a4 += p.x; a5 += p.y;
            p = __half22float2(h0[3]); a6 += p.x; a7 += p.y;
            p = __half22float2(h1[0]); a0 += p.x; a1 += p.y;
            p = __half22float2(h1[1]); a2 += p.x; a3 += p.y;
            p = __half22float2(h1[2]); a4 += p.x; a5 += p.y;
            p = __half22float2(h1[3]); a6 += p.x; a7 += p.y;
            p = __half22float2(h2[0]); a0 += p.x; a1 += p.y;
            p = __half22float2(h2[1]); a2 += p.x; a3 += p.y;
            p = __half22float2(h2[2]); a4 += p.x; a5 += p.y;
            p = __half22float2(h2[3]); a6 += p.x; a7 += p.y;
            p = __half22float2(h3[0]); a0 += p.x; a1 += p.y;
            p = __half22float2(h3[1]); a2 += p.x; a3 += p.y;
            p = __half22float2(h3[2]); a4 += p.x; a5 += p.y;
            p = __half22float2(h3[3]); a6 += p.x; a7 += p.y;
        }
        for (; j < end; j += 8) {
            int s0 = col[j];
            float4 r0 = *(const float4*)(tin + (size_t)s0 * 64 + fl * 8);
            const __half2* h0 = (const __half2*)&r0;
            float2 p;
            p = __half22float2(h0[0]); a0 += p.x; a1 += p.y;
            p = __half22float2(h0[1]); a2 += p.x; a3 += p.y;
            p = __half22float2(h0[2]); a4 += p.x; a5 += p.y;
            p = __half22float2(h0[3]); a6 += p.x; a7 += p.y;
        }
    }
#pragma unroll
    for (int m = 8; m < 64; m <<= 1) {
        a0 += __shfl_xor(a0, m, 64);
        a1 += __shfl_xor(a1, m, 64);
        a2 += __shfl_xor(a2, m, 64);
        a3 += __shfl_xor(a3, m, 64);
        a4 += __shfl_xor(a4, m, 64);
        a5 += __shfl_xor(a5, m, 64);
        a6 += __shfl_xor(a6, m, 64);
        a7 += __shfl_xor(a7, m, 64);
    }
    if (slot == 0 && node < n) {
        float dv = dinv[node];
        int fo = fl * 8;
        float4 w0, w1;
        w0.x = fmaxf(dv * a0 + bias[fo + 0], 0.f);
        w0.y = fmaxf(dv * a1 + bias[fo + 1], 0.f);
        w0.z = fmaxf(dv * a2 + bias[fo + 2], 0.f);
        w0.w = fmaxf(dv * a3 + bias[fo + 3], 0.f);
        w1.x = fmaxf(dv * a4 + bias[fo + 4], 0.f);
        w1.y = fmaxf(dv * a5 + bias[fo + 5], 0.f);
        w1.z = fmaxf(dv * a6 + bias[fo + 6], 0.f);
        w1.w = fmaxf(dv * a7 + bias[fo + 7], 0.f);
        *(float4*)&Hl[wv][fo] = w0;
        *(float4*)&Hl[wv][fo + 4] = w1;
    }
    __syncthreads();
    if (node < n && lane < 8) {
        __half o = __float2half(0.f);
        if (lane < 6) {
            float acc = 0.f;
#pragma unroll
            for (int k = 0; k < 64; ++k) acc += Hl[wv][k] * Wl6[k * 6 + lane];
            o = __float2half(acc * dinv[node]);
        }
        t6p[(size_t)node * 8 + lane] = o;
    }
}

// 6-wide aggregation over fp16 padded rows (1.6MB, L2-resident)
__global__ __launch_bounds__(256) void k_agg6(const __half* __restrict__ t6p,
                                              const int* __restrict__ rowptr,
                                              const int* __restrict__ col,
                                              const float* __restrict__ dinv,
                                              const float* __restrict__ bout,
                                              float* __restrict__ out, int n) {
    int i = blockIdx.x * 256 + threadIdx.x;
    if (i >= n) return;
    float a0 = 0.f, a1 = 0.f, a2 = 0.f, a3 = 0.f, a4 = 0.f, a5 = 0.f;
    int beg = rowptr[i], end = rowptr[i + 1];
    int j = beg;
    for (; j + 1 < end; j += 2) {
        int s0 = col[j], s1 = col[j + 1];
        float4 r0 = *(const float4*)(t6p + (size_t)s0 * 8);
        float4 r1 = *(const float4*)(t6p + (size_t)s1 * 8);
        const __half2* h0 = (const __half2*)&r0;
        const __half2* h1 = (const __half2*)&r1;
        float2 p;
        p = __half22float2(h0[0]); a0 += p.x; a1 += p.y;
        p = __half22float2(h0[1]); a2 += p.x; a3 += p.y;
        p = __half22float2(h0[2]); a4 += p.x; a5 += p.y;
        p = __half22float2(h1[0]); a0 += p.x; a1 += p.y;
        p = __half22float2(h1[1]); a2 += p.x; a3 += p.y;
        p = __half22float2(h1[2]); a4 += p.x; a5 += p.y;
    }
    if (j < end) {
        int s0 = col[j];
        float4 r0 = *(const float4*)(t6p + (size_t)s0 * 8);
        const __half2* h0 = (const __half2*)&r0;
        float2 p;
        p = __half22float2(h0[0]); a0 += p.x; a1 += p.y;
        p = __half22float2(h0[1]); a2 += p.x; a3 += p.y;
        p = __half22float2(h0[2]); a4 += p.x; a5 += p.y;
    }
    float dv = dinv[i];
    out[i * 6 + 0] = 1.0f / (1.0f + expf(-(dv * a0 + bout[0])));
    out[i * 6 + 1] = 1.0f / (1.0f + expf(-(dv * a1 + bout[1])));
    out[i * 6 + 2] = 1.0f / (1.0f + expf(-(dv * a2 + bout[2])));
    out[i * 6 + 3] = 1.0f / (1.0f + expf(-(dv * a3 + bout[3])));
    out[i * 6 + 4] = 1.0f / (1.0f + expf(-(dv * a4 + bout[4])));
    out[i * 6 + 5] = 1.0f / (1.0f + expf(-(dv * a5 + bout[5])));
}

// ---------------- host launcher ----------------

extern "C" void kernel_launch(void* const* d_in, const int* in_sizes, int n_in,
                              void* d_out, int out_size, void* d_ws, size_t ws_size,
                              hipStream_t stream) {
    const float* x    = (const float*)d_in[0];
    const int*   eidx = (const int*)d_in[1];
    const float* Win  = (const float*)d_in[2];
    const float* bin  = (const float*)d_in[3];
    const float* Whid = (const float*)d_in[4];
    const float* bhid = (const float*)d_in[5];
    const float* Wout = (const float*)d_in[6];
    const float* bout = (const float*)d_in[7];
    float* out = (float*)d_out;

    const int N = in_sizes[0] / 3;
    const int E = in_sizes[1] / 2;
    const int* srcA = eidx;
    const int* dstA = eidx + E;
    const int TOT = E + N;
    const int NBKT = (N + 255) >> 8;

    char* p = (char*)d_ws;
    auto alloc = [&](size_t bytes) -> void* {
        void* r = (void*)p;
        p += (bytes + 255) & ~(size_t)255;
        return r;
    };
    float*        dinv      = (float*)alloc((size_t)N * 4);
    int*          rowptr    = (int*)alloc((size_t)(N + 1) * 4);
    int*          bucketCnt = (int*)alloc((size_t)MAXBKT * 4);
    int*          bucketOff = (int*)alloc((size_t)(MAXBKT + 1) * 4);
    int*          bucketCur = (int*)alloc((size_t)MAXBKT * 4);
    unsigned int* bedges    = (unsigned int*)alloc((size_t)TOT * 4);
    int*          col       = (int*)alloc((size_t)TOT * 4);
    float*        xs        = (float*)alloc((size_t)N * 3 * 4);
    float*        agg3buf   = (float*)alloc((size_t)N * 3 * 4);
    __half*       tA        = (__half*)alloc((size_t)N * 64 * 2);
    __half*       tB        = (__half*)alloc((size_t)N * 64 * 2);
    __half*       t6p       = (__half*)alloc((size_t)N * 8 * 2);

    const int NB_N = (N + 255) / 256;
    const int NB8  = (N + 7) / 8;

    // CSR build
    hipMemsetAsync(bucketCnt, 0, (size_t)MAXBKT * 4, stream);
    k_bcount<<<512, 256, 0, stream>>>(dstA, E, N, NBKT, bucketCnt);
    k_bscan<<<1, MAXBKT, 0, stream>>>(bucketCnt, bucketOff, bucketCur, NBKT, TOT);
    const int CHUNK = (TOT + 511) / 512;
    k_bscat2<<<512, 256, 0, stream>>>(srcA, dstA, bucketCur, bedges, E, N, NBKT, CHUNK);
    k_bfill2<<<NBKT, 256, 0, stream>>>(bedges, bucketOff, x, rowptr, dinv, xs, col, N, TOT);

    // input layer: agg3 -> fused tin+matmul(W_hid[0]) -> t1
    k_agg3<<<NB_N, 256, 0, stream>>>(xs, rowptr, col, dinv, agg3buf, N);
    k_tin_mm<<<NB8, 512, 0, stream>>>(agg3buf, Win, bin, Whid, dinv, tA, N);

    // hidden layers 1..5 fused: t_i -> h_i -> t_{i+1}
    __half* tin = tA;
    __half* tnx = tB;
    for (int i = 1; i <= 5; ++i) {
        k_aggmm64<<<NB8, 512, 0, stream>>>(tin, rowptr, col, dinv,
                                           bhid + (size_t)(i - 1) * 64,
                                           Whid + (size_t)i * 4096, tnx, N);
        __half* tmp = tin; tin = tnx; tnx = tmp;
    }

    // last hidden + output transform fused: t6 -> h6 -> t6p
    k_aggtout<<<NB8, 512, 0, stream>>>(tin, rowptr, col, dinv,
                                       bhid + (size_t)5 * 64, Wout, t6p, N);

    // final aggregation + sigmoid
    k_agg6<<<NB_N, 256, 0, stream>>>(t6p, rowptr, col, dinv, bout, out, N);
}